// Round 17
// baseline (102.882 us; speedup 1.0000x reference)
//
#include <hip/hip_runtime.h>
#include <hip/hip_fp16.h>
#include <math.h>

#define NN 100000
#define NE 1600000
#define D 64
#define NEG_SLOPE 0.2f
#define NBKT 391          // ceil(NN/256) buckets of 256 dst nodes
#define NBIN 391          // bin blocks
#define CHUNKB 4096       // edges per bin block (391*4096 >= NE, %4==0)
#define BSLOT 5120        // slots per bucket (mean 4096, sd 64)
#define NTILE 1563        // ceil(NN/64) tiles (GEMM / elr)

typedef __attribute__((ext_vector_type(8))) short short8;
typedef __attribute__((ext_vector_type(4))) float f32x4;

// ---------------- DPP wave reduction (VALU pipe, no LDS) ----------------
template<int CTRL>
__device__ __forceinline__ float dpp_add(float x) {
    int y = __builtin_amdgcn_update_dpp(0, __float_as_int(x), CTRL, 0xf, 0xf, true);
    return x + __int_as_float(y);
}
__device__ __forceinline__ float wave_sum63(float x) {
    x = dpp_add<0x111>(x); x = dpp_add<0x112>(x); x = dpp_add<0x114>(x);
    x = dpp_add<0x118>(x); x = dpp_add<0x142>(x); x = dpp_add<0x143>(x);
    return x;
}
__device__ __forceinline__ float rdlane_f(float v, int l) {
    return __int_as_float(__builtin_amdgcn_readlane(__float_as_int(v), l));
}
// RNE float->bf16 bits
__device__ __forceinline__ unsigned bf16_1(float f) {
    unsigned x = __float_as_uint(f);
    return (x + 0x7fffu + ((x >> 16) & 1u)) >> 16;
}
__device__ __forceinline__ unsigned bfpack(float a, float b) {
    return bf16_1(a) | (bf16_1(b) << 16);
}

// =====================================================================
// D1: blocks 0..NBIN-1 bin edges; blocks NBIN.. compute el/er tiles.
// =====================================================================
__global__ __launch_bounds__(256) void k_bg(
    const int* __restrict__ src, const int* __restrict__ dst,
    unsigned* __restrict__ bcnt, unsigned* __restrict__ binned,
    const float* __restrict__ feat, const float* __restrict__ W,
    const float* __restrict__ attn_l, const float* __restrict__ attn_r,
    float* __restrict__ el, float* __restrict__ er)
{
    __shared__ __align__(16) char smem[1664];
    int t = threadIdx.x;

    if (blockIdx.x < NBIN) {
        // ---- bin: histogram + self-reserve (slotted buckets) + scatter ----
        unsigned* lh = (unsigned*)smem;               // NBKT counters
        unsigned b0 = blockIdx.x * CHUNKB;
        unsigned b1 = min(b0 + CHUNKB, (unsigned)NE);
        if (b0 >= b1) return;
        unsigned n4 = (b1 - b0) >> 2;
        for (int k = t; k < NBKT; k += 256) lh[k] = 0u;
        __syncthreads();
        const int4* d4 = (const int4*)(dst + b0);
        const int4* s4 = (const int4*)(src + b0);
        for (unsigned i = t; i < n4; i += 256) {
            int4 v = d4[i];
            atomicAdd(&lh[((unsigned)v.x) >> 8], 1u);
            atomicAdd(&lh[((unsigned)v.y) >> 8], 1u);
            atomicAdd(&lh[((unsigned)v.z) >> 8], 1u);
            atomicAdd(&lh[((unsigned)v.w) >> 8], 1u);
        }
        __syncthreads();
        for (int k = t; k < NBKT; k += 256) {
            unsigned c = lh[k];
            if (c) lh[k] = (unsigned)k * BSLOT + atomicAdd(&bcnt[k], c);
        }
        __syncthreads();
        for (unsigned i = t; i < n4; i += 256) {
            int4 dv = d4[i];
            int4 sv = s4[i];
            { unsigned d_=(unsigned)dv.x, s_=(unsigned)sv.x;
              unsigned pos=atomicAdd(&lh[d_>>8],1u); binned[pos]=(s_<<8)|(d_&255u); }
            { unsigned d_=(unsigned)dv.y, s_=(unsigned)sv.y;
              unsigned pos=atomicAdd(&lh[d_>>8],1u); binned[pos]=(s_<<8)|(d_&255u); }
            { unsigned d_=(unsigned)dv.z, s_=(unsigned)sv.z;
              unsigned pos=atomicAdd(&lh[d_>>8],1u); binned[pos]=(s_<<8)|(d_&255u); }
            { unsigned d_=(unsigned)dv.w, s_=(unsigned)sv.w;
              unsigned pos=atomicAdd(&lh[d_>>8],1u); binned[pos]=(s_<<8)|(d_&255u); }
        }
        return;
    }

    // ---- elr tile: el/er for 64 nodes (exact fp32: feat . (W@attn)) ----
    float* wlS = (float*)smem;
    float* wrS = (float*)(smem + 256);
    int n0 = (int)(blockIdx.x - NBIN) * 64;
    {
        int k = t >> 2, s = t & 3;
        float pl = 0.f, pr = 0.f;
        #pragma unroll
        for (int q = 0; q < 4; ++q) {
            int seg = s + q * 4;
            float4 f = *(const float4*)(W + k * 64 + seg * 4);
            float4 a = *(const float4*)(attn_l + seg * 4);
            float4 b = *(const float4*)(attn_r + seg * 4);
            pl += f.x*a.x + f.y*a.y + f.z*a.z + f.w*a.w;
            pr += f.x*b.x + f.y*b.y + f.z*b.z + f.w*b.w;
        }
        pl += __shfl_xor(pl, 1, 64); pl += __shfl_xor(pl, 2, 64);
        pr += __shfl_xor(pr, 1, 64); pr += __shfl_xor(pr, 2, 64);
        if (s == 0) { wlS[k] = pl; wrS[k] = pr; }
    }
    __syncthreads();
    {
        int r = t >> 2, s = t & 3;
        int n = n0 + r;
        bool valid = n < NN;
        const float* fp = feat + (size_t)(valid ? n : (NN - 1)) * D;
        float pl = 0.f, pr = 0.f;
        #pragma unroll
        for (int q = 0; q < 4; ++q) {
            int seg = s + q * 4;
            float4 f = *(const float4*)(fp + seg * 4);
            float4 a = *(const float4*)(wlS + seg * 4);
            float4 b = *(const float4*)(wrS + seg * 4);
            pl += f.x*a.x + f.y*a.y + f.z*a.z + f.w*a.w;
            pr += f.x*b.x + f.y*b.y + f.z*b.z + f.w*b.w;
        }
        pl += __shfl_xor(pl, 1, 64); pl += __shfl_xor(pl, 2, 64);
        pr += __shfl_xor(pr, 1, 64); pr += __shfl_xor(pr, 2, 64);
        if (s == 0 && valid) { el[n] = pl; er[n] = pr; }
    }
}

// =====================================================================
// D2: blocks 0..NBKT-1 counting-sort + fuse exp(leaky(el+er)) -> eperm;
// blocks NBKT.. run MFMA GEMM tiles (no el/er work).
// =====================================================================
__global__ __launch_bounds__(256) void k_sg(
    const unsigned* __restrict__ bcnt, const unsigned* __restrict__ binned,
    const float* __restrict__ el, const float* __restrict__ er,
    int* __restrict__ perm, float* __restrict__ eperm, uint2* __restrict__ rowBE,
    const float* __restrict__ feat, const float* __restrict__ W,
    __half* __restrict__ ft)
{
    __shared__ __align__(16) char smem[22784];
    int t = threadIdx.x;

    if (blockIdx.x < NBKT) {
        unsigned* lh    = (unsigned*)smem;            // 256
        unsigned* cur   = (unsigned*)smem + 256;      // 256
        unsigned* stage = (unsigned*)smem + 512;      // BSLOT
        int b = blockIdx.x;
        unsigned beg = (unsigned)b * BSLOT;
        unsigned cnt = min(bcnt[b], (unsigned)BSLOT);
        lh[t] = 0u;
        __syncthreads();
        for (unsigned i = t; i < cnt; i += 256) {
            unsigned w = binned[beg + i];
            stage[i] = w;
            atomicAdd(&lh[w & 255u], 1u);
        }
        __syncthreads();
        for (int off = 1; off < 256; off <<= 1) {     // inclusive scan
            unsigned u = (t >= off) ? lh[t - off] : 0u;
            __syncthreads();
            lh[t] += u;
            __syncthreads();
        }
        unsigned start = (t == 0) ? 0u : lh[t - 1];
        unsigned node = ((unsigned)b << 8) + (unsigned)t;
        if (node < NN) {
            uint2 be; be.x = beg + start; be.y = beg + lh[t];
            rowBE[node] = be;
        }
        cur[t] = start;
        __syncthreads();
        // scatter: write sorted src AND the unnormalized softmax weight
        for (unsigned i = t; i < cnt; i += 256) {
            unsigned w = stage[i];
            unsigned dl = w & 255u;
            unsigned pos = atomicAdd(&cur[dl], 1u);
            unsigned sj = w >> 8;
            float e = el[sj] + er[((unsigned)b << 8) + dl];
            e = e > 0.0f ? e : NEG_SLOPE * e;
            perm[beg + pos] = (int)sj;
            eperm[beg + pos] = __expf(e);       // eperm aliases binned (read done)
        }
        __syncthreads();
        // tail-pad 8 entries so k_agg's batched overreads are benign
        if (t < 8 && cnt + t < BSLOT) {
            perm[beg + cnt + t] = 0;
            eperm[beg + cnt + t] = 0.0f;
        }
        return;
    }

    // ---------------- MFMA GEMM tile (no el/er) ----------------
    unsigned short* Ab = (unsigned short*)smem;            // 8192 B
    unsigned short* Bb = (unsigned short*)(smem + 8192);   // 8192 B
    int n0 = (int)(blockIdx.x - NBKT) * 64;
    {
        int j = t & 63, g = t >> 6;
        unsigned m = (unsigned)((j & 7) << 4);
        #pragma unroll
        for (int i = 0; i < 8; ++i) {
            int k0 = g * 16 + i * 2;
            float w0 = W[k0 * 64 + j];
            float w1 = W[(k0 + 1) * 64 + j];
            *(unsigned*)((char*)Bb + j * 128 + (((unsigned)(k0 * 2)) ^ m)) = bfpack(w0, w1);
        }
    }
    {
        int r = t >> 2, s = t & 3;
        int n = n0 + r;
        bool valid = n < NN;
        const float* fp = feat + (size_t)(valid ? n : (NN - 1)) * D;
        unsigned m = (unsigned)((r & 7) << 4);
        #pragma unroll
        for (int q = 0; q < 4; ++q) {
            int seg = s + q * 4;
            float4 f = *(const float4*)(fp + seg * 4);
            uint2 pk;
            pk.x = bfpack(f.x, f.y);
            pk.y = bfpack(f.z, f.w);
            *(uint2*)((char*)Ab + r * 128 + (((unsigned)(seg * 8)) ^ m)) = pk;
        }
    }
    __syncthreads();

    int w = t >> 6, l = t & 63;
    int lr = l & 15, lg = l >> 4;
    f32x4 acc0 = {0.f,0.f,0.f,0.f};
    f32x4 acc1 = {0.f,0.f,0.f,0.f};
    f32x4 acc2 = {0.f,0.f,0.f,0.f};
    f32x4 acc3 = {0.f,0.f,0.f,0.f};

    int jrow = w * 16 + lr;
    unsigned bm = (unsigned)((jrow & 7) << 4);
    short8 bf0 = *(const short8*)((char*)Bb + jrow * 128 + (((unsigned)(0 + lg * 16)) ^ bm));
    short8 bf1 = *(const short8*)((char*)Bb + jrow * 128 + (((unsigned)(64 + lg * 16)) ^ bm));

    #pragma unroll
    for (int rt = 0; rt < 4; ++rt) {
        int arow = rt * 16 + lr;
        unsigned am = (unsigned)((arow & 7) << 4);
        short8 a0 = *(const short8*)((char*)Ab + arow * 128 + (((unsigned)(0 + lg * 16)) ^ am));
        short8 a1 = *(const short8*)((char*)Ab + arow * 128 + (((unsigned)(64 + lg * 16)) ^ am));
        f32x4 acc = (rt == 0) ? acc0 : (rt == 1) ? acc1 : (rt == 2) ? acc2 : acc3;
        acc = __builtin_amdgcn_mfma_f32_16x16x32_bf16(a0, bf0, acc, 0, 0, 0);
        acc = __builtin_amdgcn_mfma_f32_16x16x32_bf16(a1, bf1, acc, 0, 0, 0);
        if (rt == 0) acc0 = acc; else if (rt == 1) acc1 = acc;
        else if (rt == 2) acc2 = acc; else acc3 = acc;
    }

    int col = w * 16 + lr;
    #pragma unroll
    for (int rt = 0; rt < 4; ++rt) {
        f32x4 acc = (rt == 0) ? acc0 : (rt == 1) ? acc1 : (rt == 2) ? acc2 : acc3;
        #pragma unroll
        for (int i = 0; i < 4; ++i) {
            int row = rt * 16 + lg * 4 + i;
            int nn = n0 + row;
            if (nn < NN) ft[(size_t)nn * D + col] = __float2half(acc[i]);
        }
    }
}

// ---- fallback: full-wave processing of one node (deg > 64) ----
__device__ __noinline__ void agg_node64(int d, int lane, unsigned beg, unsigned end,
                                        const int* __restrict__ perm,
                                        const float* __restrict__ eperm,
                                        const __half* __restrict__ ft,
                                        const float* __restrict__ feat,
                                        const float* __restrict__ bias,
                                        float* __restrict__ out) {
    float s = 0.0f;
    for (unsigned base = beg; base < end; base += 64) {
        unsigned i = base + lane;
        float exx = (i < end) ? eperm[i] : 0.0f;
        s += rdlane_f(wave_sum63(exx), 63);
    }
    float inv_s = __frcp_rn(s);
    float acc = 0.0f;
    for (unsigned jj = beg; jj < end; ++jj) {
        int sj = perm[jj];
        float wj = eperm[jj];
        acc = fmaf(__half2float(ft[((size_t)(unsigned)sj << 6) + lane]), wj, acc);
    }
    acc *= inv_s;
    out[(size_t)d * D + lane] = acc + feat[(size_t)d * D + lane] + bias[lane];
}

// scalar-pipe gather: sids via uniform (s_load) reads, saddr-form row loads
#define LOAD8(B, J) do { \
    int _s0 = ps[(J)+0]; int _s1 = ps[(J)+1]; int _s2 = ps[(J)+2]; int _s3 = ps[(J)+3]; \
    int _s4 = ps[(J)+4]; int _s5 = ps[(J)+5]; int _s6 = ps[(J)+6]; int _s7 = ps[(J)+7]; \
    B##0 = *(const __half*)(ftb + (((size_t)(unsigned)_s0) << 7) + lb); \
    B##1 = *(const __half*)(ftb + (((size_t)(unsigned)_s1) << 7) + lb); \
    B##2 = *(const __half*)(ftb + (((size_t)(unsigned)_s2) << 7) + lb); \
    B##3 = *(const __half*)(ftb + (((size_t)(unsigned)_s3) << 7) + lb); \
    B##4 = *(const __half*)(ftb + (((size_t)(unsigned)_s4) << 7) + lb); \
    B##5 = *(const __half*)(ftb + (((size_t)(unsigned)_s5) << 7) + lb); \
    B##6 = *(const __half*)(ftb + (((size_t)(unsigned)_s6) << 7) + lb); \
    B##7 = *(const __half*)(ftb + (((size_t)(unsigned)_s7) << 7) + lb); \
} while (0)

#define FMA8(B, J) do { \
    acc = fmaf(__half2float(B##0), rdlane_f(ex, (J) + 0), acc); \
    acc = fmaf(__half2float(B##1), rdlane_f(ex, (J) + 1), acc); \
    acc = fmaf(__half2float(B##2), rdlane_f(ex, (J) + 2), acc); \
    acc = fmaf(__half2float(B##3), rdlane_f(ex, (J) + 3), acc); \
    acc = fmaf(__half2float(B##4), rdlane_f(ex, (J) + 4), acc); \
    acc = fmaf(__half2float(B##5), rdlane_f(ex, (J) + 5), acc); \
    acc = fmaf(__half2float(B##6), rdlane_f(ex, (J) + 6), acc); \
    acc = fmaf(__half2float(B##7), rdlane_f(ex, (J) + 7), acc); \
} while (0)

// fused aggregation: weights precomputed (eperm); one wave per node.
__global__ __launch_bounds__(256) void k_agg(const uint2* __restrict__ rowBE,
                                             const int* __restrict__ perm,
                                             const float* __restrict__ eperm,
                                             const __half* __restrict__ ft,
                                             const float* __restrict__ feat,
                                             const float* __restrict__ bias,
                                             float* __restrict__ out) {
    int gid = blockIdx.x * 256 + threadIdx.x;
    int d = gid >> 6;
    int lane = gid & 63;
    if (d >= NN) return;

    uint2 be = rowBE[d];
    unsigned beg = be.x;
    int deg = (int)(be.y - be.x);

    if (deg > 64) {
        agg_node64(d, lane, be.x, be.y, perm, eperm, ft, feat, bias, out);
        return;
    }
    if (deg == 0) {
        out[(size_t)d * D + lane] = feat[(size_t)d * D + lane] + bias[lane];
        return;
    }

    float ex = (lane < deg) ? eperm[beg + lane] : 0.0f;   // coalesced weight load
    float fv = feat[(size_t)d * D + lane];
    float bv = bias[lane];

    unsigned begu = __builtin_amdgcn_readfirstlane(beg);
    int degu = __builtin_amdgcn_readfirstlane(deg);
    const int* ps = perm + begu;              // uniform base -> s_load batches
    const char* ftb = (const char*)ft;
    size_t lb = (size_t)((unsigned)lane << 1);

    __half c0, c1, c2, c3, c4, c5, c6, c7;
    __half n0, n1, n2, n3, n4, n5, n6, n7;
    LOAD8(c, 0);                              // batch 0 in flight during sum

    float s = rdlane_f(wave_sum63(ex), 63);
    float inv_s = __frcp_rn(s);

    float acc = 0.0f;
    int j = 0;
    while (true) {
        bool more = (j + 8) < degu;
        if (more) LOAD8(n, j + 8);
        FMA8(c, j);
        j += 8;
        if (!more) break;
        bool more2 = (j + 8) < degu;
        if (more2) LOAD8(c, j + 8);
        FMA8(n, j);
        j += 8;
        if (!more2) break;
    }
    acc *= inv_s;
    out[(size_t)d * D + lane] = acc + fv + bv;
}

extern "C" void kernel_launch(void* const* d_in, const int* in_sizes, int n_in,
                              void* d_out, int out_size, void* d_ws, size_t ws_size,
                              hipStream_t stream) {
    const float* feat   = (const float*)d_in[0];
    const float* W      = (const float*)d_in[1];
    const float* attn_l = (const float*)d_in[2];
    const float* attn_r = (const float*)d_in[3];
    const float* bias   = (const float*)d_in[4];
    const int*   src    = (const int*)d_in[5];
    const int*   dst    = (const int*)d_in[6];
    float* out = (float*)d_out;

    char* ws = (char*)d_ws;
    __half*   ft     = (__half*)(ws);                // 12,800,000
    float*    el     = (float*)(ws + 12800000);      // 400,000
    float*    er     = (float*)(ws + 13200000);      // 400,000
    int*      perm   = (int*)(ws + 13600000);        // 8,007,680 -> 21,607,680
    uint2*    rowBE  = (uint2*)(ws + 21607680);      // 800,000 -> 22,407,680
    unsigned* bcnt   = (unsigned*)(ws + 22407680);   // 1,564 -> 22,409,244
    unsigned* binned = (unsigned*)(ws + 22409248);   // 8,007,680 -> 30,416,928
    float*    eperm  = (float*)binned;               // aliases binned (sort stages
                                                     // its bucket in LDS first)

    hipMemsetAsync(bcnt, 0, NBKT * sizeof(unsigned), stream);
    k_bg<<<NBIN + NTILE, 256, 0, stream>>>(src, dst, bcnt, binned,
                                           feat, W, attn_l, attn_r, el, er);
    k_sg<<<NBKT + NTILE, 256, 0, stream>>>(bcnt, binned, el, er,
                                           perm, eperm, rowBE, feat, W, ft);
    k_agg<<<(NN * 64 + 255) / 256, 256, 0, stream>>>(rowBE, perm, eperm,
                                                     ft, feat, bias, out);
}

// Round 18
// 97.300 us; speedup vs baseline: 1.0574x; 1.0574x over previous
//
#include <hip/hip_runtime.h>
#include <hip/hip_fp16.h>
#include <math.h>

#define NN 100000
#define NE 1600000
#define D 64
#define NEG_SLOPE 0.2f
#define NBKT 391          // ceil(NN/256) buckets of 256 dst nodes
#define NBIN 391          // bin blocks
#define CHUNKB 4096       // edges per bin block (391*4096 >= NE, %4==0)
#define BSLOT 5120        // slots per bucket (mean 4096, sd 64)
#define NTILE 1563        // ceil(NN/64) tiles (GEMM / elr)

typedef __attribute__((ext_vector_type(8))) short short8;
typedef __attribute__((ext_vector_type(4))) float f32x4;

// ---------------- DPP wave reduction (VALU pipe, no LDS) ----------------
template<int CTRL>
__device__ __forceinline__ float dpp_add(float x) {
    int y = __builtin_amdgcn_update_dpp(0, __float_as_int(x), CTRL, 0xf, 0xf, true);
    return x + __int_as_float(y);
}
__device__ __forceinline__ float wave_sum63(float x) {
    x = dpp_add<0x111>(x); x = dpp_add<0x112>(x); x = dpp_add<0x114>(x);
    x = dpp_add<0x118>(x); x = dpp_add<0x142>(x); x = dpp_add<0x143>(x);
    return x;
}
__device__ __forceinline__ float rdlane_f(float v, int l) {
    return __int_as_float(__builtin_amdgcn_readlane(__float_as_int(v), l));
}
// RNE float->bf16 bits
__device__ __forceinline__ unsigned bf16_1(float f) {
    unsigned x = __float_as_uint(f);
    return (x + 0x7fffu + ((x >> 16) & 1u)) >> 16;
}
__device__ __forceinline__ unsigned bfpack(float a, float b) {
    return bf16_1(a) | (bf16_1(b) << 16);
}

// ---- D0: zero bcnt (replaces the 40us fillBuffer graph node) ----
__global__ __launch_bounds__(256) void k_zero(unsigned* __restrict__ bcnt) {
    int i = blockIdx.x * 256 + threadIdx.x;
    if (i < NBKT) bcnt[i] = 0u;
}

// =====================================================================
// D1: blocks 0..NBIN-1 bin edges; blocks NBIN.. compute el/er tiles.
// =====================================================================
__global__ __launch_bounds__(256) void k_bg(
    const int* __restrict__ src, const int* __restrict__ dst,
    unsigned* __restrict__ bcnt, unsigned* __restrict__ binned,
    const float* __restrict__ feat, const float* __restrict__ W,
    const float* __restrict__ attn_l, const float* __restrict__ attn_r,
    float* __restrict__ el, float* __restrict__ er)
{
    __shared__ __align__(16) char smem[1664];
    int t = threadIdx.x;

    if (blockIdx.x < NBIN) {
        unsigned* lh = (unsigned*)smem;               // NBKT counters
        unsigned b0 = blockIdx.x * CHUNKB;
        unsigned b1 = min(b0 + CHUNKB, (unsigned)NE);
        if (b0 >= b1) return;
        unsigned n4 = (b1 - b0) >> 2;
        for (int k = t; k < NBKT; k += 256) lh[k] = 0u;
        __syncthreads();
        const int4* d4 = (const int4*)(dst + b0);
        const int4* s4 = (const int4*)(src + b0);
        for (unsigned i = t; i < n4; i += 256) {
            int4 v = d4[i];
            atomicAdd(&lh[((unsigned)v.x) >> 8], 1u);
            atomicAdd(&lh[((unsigned)v.y) >> 8], 1u);
            atomicAdd(&lh[((unsigned)v.z) >> 8], 1u);
            atomicAdd(&lh[((unsigned)v.w) >> 8], 1u);
        }
        __syncthreads();
        for (int k = t; k < NBKT; k += 256) {
            unsigned c = lh[k];
            if (c) lh[k] = (unsigned)k * BSLOT + atomicAdd(&bcnt[k], c);
        }
        __syncthreads();
        for (unsigned i = t; i < n4; i += 256) {
            int4 dv = d4[i];
            int4 sv = s4[i];
            { unsigned d_=(unsigned)dv.x, s_=(unsigned)sv.x;
              unsigned pos=atomicAdd(&lh[d_>>8],1u); binned[pos]=(s_<<8)|(d_&255u); }
            { unsigned d_=(unsigned)dv.y, s_=(unsigned)sv.y;
              unsigned pos=atomicAdd(&lh[d_>>8],1u); binned[pos]=(s_<<8)|(d_&255u); }
            { unsigned d_=(unsigned)dv.z, s_=(unsigned)sv.z;
              unsigned pos=atomicAdd(&lh[d_>>8],1u); binned[pos]=(s_<<8)|(d_&255u); }
            { unsigned d_=(unsigned)dv.w, s_=(unsigned)sv.w;
              unsigned pos=atomicAdd(&lh[d_>>8],1u); binned[pos]=(s_<<8)|(d_&255u); }
        }
        return;
    }

    // ---- elr tile: el/er for 64 nodes (exact fp32: feat . (W@attn)) ----
    float* wlS = (float*)smem;
    float* wrS = (float*)(smem + 256);
    int n0 = (int)(blockIdx.x - NBIN) * 64;
    {
        int k = t >> 2, s = t & 3;
        float pl = 0.f, pr = 0.f;
        #pragma unroll
        for (int q = 0; q < 4; ++q) {
            int seg = s + q * 4;
            float4 f = *(const float4*)(W + k * 64 + seg * 4);
            float4 a = *(const float4*)(attn_l + seg * 4);
            float4 b = *(const float4*)(attn_r + seg * 4);
            pl += f.x*a.x + f.y*a.y + f.z*a.z + f.w*a.w;
            pr += f.x*b.x + f.y*b.y + f.z*b.z + f.w*b.w;
        }
        pl += __shfl_xor(pl, 1, 64); pl += __shfl_xor(pl, 2, 64);
        pr += __shfl_xor(pr, 1, 64); pr += __shfl_xor(pr, 2, 64);
        if (s == 0) { wlS[k] = pl; wrS[k] = pr; }
    }
    __syncthreads();
    {
        int r = t >> 2, s = t & 3;
        int n = n0 + r;
        bool valid = n < NN;
        const float* fp = feat + (size_t)(valid ? n : (NN - 1)) * D;
        float pl = 0.f, pr = 0.f;
        #pragma unroll
        for (int q = 0; q < 4; ++q) {
            int seg = s + q * 4;
            float4 f = *(const float4*)(fp + seg * 4);
            float4 a = *(const float4*)(wlS + seg * 4);
            float4 b = *(const float4*)(wrS + seg * 4);
            pl += f.x*a.x + f.y*a.y + f.z*a.z + f.w*a.w;
            pr += f.x*b.x + f.y*b.y + f.z*b.z + f.w*b.w;
        }
        pl += __shfl_xor(pl, 1, 64); pl += __shfl_xor(pl, 2, 64);
        pr += __shfl_xor(pr, 1, 64); pr += __shfl_xor(pr, 2, 64);
        if (s == 0 && valid) { el[n] = pl; er[n] = pr; }
    }
}

// =====================================================================
// D2: blocks 0..NBKT-1 counting-sort + batched eperm pass;
// blocks NBKT.. run MFMA GEMM tiles.
// =====================================================================
__global__ __launch_bounds__(256) void k_sg(
    const unsigned* __restrict__ bcnt, const unsigned* __restrict__ binned,
    const float* __restrict__ el, const float* __restrict__ er,
    int* __restrict__ perm, float* __restrict__ eperm, uint2* __restrict__ rowBE,
    const float* __restrict__ feat, const float* __restrict__ W,
    __half* __restrict__ ft)
{
    __shared__ __align__(16) char smem[28800];
    int t = threadIdx.x;

    if (blockIdx.x < NBKT) {
        unsigned* lh    = (unsigned*)smem;                  // 1024 B
        unsigned* cur   = (unsigned*)(smem + 1024);         // 1024 B
        float*    erL   = (float*)(smem + 2048);            // 1024 B
        unsigned char* dlocL = (unsigned char*)(smem + 3072);  // 5120 B
        unsigned* stage = (unsigned*)(smem + 8192);         // 20480 B
        int b = blockIdx.x;
        unsigned beg = (unsigned)b * BSLOT;
        unsigned cnt = min(bcnt[b], (unsigned)BSLOT);
        lh[t] = 0u;
        {   // er cache for this bucket's 256 nodes
            unsigned node = ((unsigned)b << 8) + (unsigned)t;
            erL[t] = (node < NN) ? er[node] : 0.0f;
        }
        __syncthreads();
        for (unsigned i = t; i < cnt; i += 256) {
            unsigned w = binned[beg + i];
            stage[i] = w;
            atomicAdd(&lh[w & 255u], 1u);
        }
        __syncthreads();
        for (int off = 1; off < 256; off <<= 1) {     // inclusive scan
            unsigned u = (t >= off) ? lh[t - off] : 0u;
            __syncthreads();
            lh[t] += u;
            __syncthreads();
        }
        unsigned start = (t == 0) ? 0u : lh[t - 1];
        unsigned node = ((unsigned)b << 8) + (unsigned)t;
        if (node < NN) {
            uint2 be; be.x = beg + start; be.y = beg + lh[t];
            rowBE[node] = be;
        }
        cur[t] = start;
        __syncthreads();
        // scatter: perm to global, dloc to LDS
        for (unsigned i = t; i < cnt; i += 256) {
            unsigned w = stage[i];
            unsigned dl = w & 255u;
            unsigned pos = atomicAdd(&cur[dl], 1u);
            perm[beg + pos] = (int)(w >> 8);
            dlocL[pos] = (unsigned char)dl;
        }
        __syncthreads();
        // batched eperm pass: 4 independent el-gathers in flight
        {
            unsigned i = t;
            for (; i + 768 < cnt; i += 1024) {
                int sj0 = perm[beg + i];
                int sj1 = perm[beg + i + 256];
                int sj2 = perm[beg + i + 512];
                int sj3 = perm[beg + i + 768];
                float e0 = el[sj0] + erL[dlocL[i]];
                float e1 = el[sj1] + erL[dlocL[i + 256]];
                float e2 = el[sj2] + erL[dlocL[i + 512]];
                float e3 = el[sj3] + erL[dlocL[i + 768]];
                e0 = e0 > 0.f ? e0 : NEG_SLOPE * e0;
                e1 = e1 > 0.f ? e1 : NEG_SLOPE * e1;
                e2 = e2 > 0.f ? e2 : NEG_SLOPE * e2;
                e3 = e3 > 0.f ? e3 : NEG_SLOPE * e3;
                eperm[beg + i]       = __expf(e0);
                eperm[beg + i + 256] = __expf(e1);
                eperm[beg + i + 512] = __expf(e2);
                eperm[beg + i + 768] = __expf(e3);
            }
            for (; i < cnt; i += 256) {
                int sj = perm[beg + i];
                float e = el[sj] + erL[dlocL[i]];
                e = e > 0.f ? e : NEG_SLOPE * e;
                eperm[beg + i] = __expf(e);
            }
        }
        // tail-pad 8 entries so k_agg's batched overreads are benign
        if (t < 8 && cnt + t < BSLOT) {
            perm[beg + cnt + t] = 0;
            eperm[beg + cnt + t] = 0.0f;
        }
        return;
    }

    // ---------------- MFMA GEMM tile ----------------
    unsigned short* Ab = (unsigned short*)smem;            // 8192 B
    unsigned short* Bb = (unsigned short*)(smem + 8192);   // 8192 B
    int n0 = (int)(blockIdx.x - NBKT) * 64;
    {
        int j = t & 63, g = t >> 6;
        unsigned m = (unsigned)((j & 7) << 4);
        #pragma unroll
        for (int i = 0; i < 8; ++i) {
            int k0 = g * 16 + i * 2;
            float w0 = W[k0 * 64 + j];
            float w1 = W[(k0 + 1) * 64 + j];
            *(unsigned*)((char*)Bb + j * 128 + (((unsigned)(k0 * 2)) ^ m)) = bfpack(w0, w1);
        }
    }
    {
        int r = t >> 2, s = t & 3;
        int n = n0 + r;
        bool valid = n < NN;
        const float* fp = feat + (size_t)(valid ? n : (NN - 1)) * D;
        unsigned m = (unsigned)((r & 7) << 4);
        #pragma unroll
        for (int q = 0; q < 4; ++q) {
            int seg = s + q * 4;
            float4 f = *(const float4*)(fp + seg * 4);
            uint2 pk;
            pk.x = bfpack(f.x, f.y);
            pk.y = bfpack(f.z, f.w);
            *(uint2*)((char*)Ab + r * 128 + (((unsigned)(seg * 8)) ^ m)) = pk;
        }
    }
    __syncthreads();

    int w = t >> 6, l = t & 63;
    int lr = l & 15, lg = l >> 4;
    f32x4 acc0 = {0.f,0.f,0.f,0.f};
    f32x4 acc1 = {0.f,0.f,0.f,0.f};
    f32x4 acc2 = {0.f,0.f,0.f,0.f};
    f32x4 acc3 = {0.f,0.f,0.f,0.f};

    int jrow = w * 16 + lr;
    unsigned bm = (unsigned)((jrow & 7) << 4);
    short8 bf0 = *(const short8*)((char*)Bb + jrow * 128 + (((unsigned)(0 + lg * 16)) ^ bm));
    short8 bf1 = *(const short8*)((char*)Bb + jrow * 128 + (((unsigned)(64 + lg * 16)) ^ bm));

    #pragma unroll
    for (int rt = 0; rt < 4; ++rt) {
        int arow = rt * 16 + lr;
        unsigned am = (unsigned)((arow & 7) << 4);
        short8 a0 = *(const short8*)((char*)Ab + arow * 128 + (((unsigned)(0 + lg * 16)) ^ am));
        short8 a1 = *(const short8*)((char*)Ab + arow * 128 + (((unsigned)(64 + lg * 16)) ^ am));
        f32x4 acc = (rt == 0) ? acc0 : (rt == 1) ? acc1 : (rt == 2) ? acc2 : acc3;
        acc = __builtin_amdgcn_mfma_f32_16x16x32_bf16(a0, bf0, acc, 0, 0, 0);
        acc = __builtin_amdgcn_mfma_f32_16x16x32_bf16(a1, bf1, acc, 0, 0, 0);
        if (rt == 0) acc0 = acc; else if (rt == 1) acc1 = acc;
        else if (rt == 2) acc2 = acc; else acc3 = acc;
    }

    int col = w * 16 + lr;
    #pragma unroll
    for (int rt = 0; rt < 4; ++rt) {
        f32x4 acc = (rt == 0) ? acc0 : (rt == 1) ? acc1 : (rt == 2) ? acc2 : acc3;
        #pragma unroll
        for (int i = 0; i < 4; ++i) {
            int row = rt * 16 + lg * 4 + i;
            int nn = n0 + row;
            if (nn < NN) ft[(size_t)nn * D + col] = __float2half(acc[i]);
        }
    }
}

// ---- fallback: full-wave processing of one node (deg > 64) ----
__device__ __noinline__ void agg_node64(int d, int lane, unsigned beg, unsigned end,
                                        const int* __restrict__ perm,
                                        const float* __restrict__ eperm,
                                        const __half* __restrict__ ft,
                                        const float* __restrict__ feat,
                                        const float* __restrict__ bias,
                                        float* __restrict__ out) {
    float s = 0.0f;
    for (unsigned base = beg; base < end; base += 64) {
        unsigned i = base + lane;
        float exx = (i < end) ? eperm[i] : 0.0f;
        s += rdlane_f(wave_sum63(exx), 63);
    }
    float inv_s = __frcp_rn(s);
    float acc = 0.0f;
    for (unsigned jj = beg; jj < end; ++jj) {
        int sj = perm[jj];
        float wj = eperm[jj];
        acc = fmaf(__half2float(ft[((size_t)(unsigned)sj << 6) + lane]), wj, acc);
    }
    acc *= inv_s;
    out[(size_t)d * D + lane] = acc + feat[(size_t)d * D + lane] + bias[lane];
}

// scalar-pipe gather: sids via uniform (s_load) reads, saddr-form row loads
#define LOAD8(B, J) do { \
    int _s0 = ps[(J)+0]; int _s1 = ps[(J)+1]; int _s2 = ps[(J)+2]; int _s3 = ps[(J)+3]; \
    int _s4 = ps[(J)+4]; int _s5 = ps[(J)+5]; int _s6 = ps[(J)+6]; int _s7 = ps[(J)+7]; \
    B##0 = *(const __half*)(ftb + (((size_t)(unsigned)_s0) << 7) + lb); \
    B##1 = *(const __half*)(ftb + (((size_t)(unsigned)_s1) << 7) + lb); \
    B##2 = *(const __half*)(ftb + (((size_t)(unsigned)_s2) << 7) + lb); \
    B##3 = *(const __half*)(ftb + (((size_t)(unsigned)_s3) << 7) + lb); \
    B##4 = *(const __half*)(ftb + (((size_t)(unsigned)_s4) << 7) + lb); \
    B##5 = *(const __half*)(ftb + (((size_t)(unsigned)_s5) << 7) + lb); \
    B##6 = *(const __half*)(ftb + (((size_t)(unsigned)_s6) << 7) + lb); \
    B##7 = *(const __half*)(ftb + (((size_t)(unsigned)_s7) << 7) + lb); \
} while (0)

#define FMA8(B, J) do { \
    acc = fmaf(__half2float(B##0), rdlane_f(ex, (J) + 0), acc); \
    acc = fmaf(__half2float(B##1), rdlane_f(ex, (J) + 1), acc); \
    acc = fmaf(__half2float(B##2), rdlane_f(ex, (J) + 2), acc); \
    acc = fmaf(__half2float(B##3), rdlane_f(ex, (J) + 3), acc); \
    acc = fmaf(__half2float(B##4), rdlane_f(ex, (J) + 4), acc); \
    acc = fmaf(__half2float(B##5), rdlane_f(ex, (J) + 5), acc); \
    acc = fmaf(__half2float(B##6), rdlane_f(ex, (J) + 6), acc); \
    acc = fmaf(__half2float(B##7), rdlane_f(ex, (J) + 7), acc); \
} while (0)

// fused aggregation: weights precomputed (eperm); one wave per node.
__global__ __launch_bounds__(256) void k_agg(const uint2* __restrict__ rowBE,
                                             const int* __restrict__ perm,
                                             const float* __restrict__ eperm,
                                             const __half* __restrict__ ft,
                                             const float* __restrict__ feat,
                                             const float* __restrict__ bias,
                                             float* __restrict__ out) {
    int gid = blockIdx.x * 256 + threadIdx.x;
    int d = gid >> 6;
    int lane = gid & 63;
    if (d >= NN) return;

    uint2 be = rowBE[d];
    unsigned beg = be.x;
    int deg = (int)(be.y - be.x);

    if (deg > 64) {
        agg_node64(d, lane, be.x, be.y, perm, eperm, ft, feat, bias, out);
        return;
    }
    if (deg == 0) {
        out[(size_t)d * D + lane] = feat[(size_t)d * D + lane] + bias[lane];
        return;
    }

    float ex = (lane < deg) ? eperm[beg + lane] : 0.0f;   // coalesced weight load
    float fv = feat[(size_t)d * D + lane];
    float bv = bias[lane];

    unsigned begu = __builtin_amdgcn_readfirstlane(beg);
    int degu = __builtin_amdgcn_readfirstlane(deg);
    const int* ps = perm + begu;              // uniform base -> s_load batches
    const char* ftb = (const char*)ft;
    size_t lb = (size_t)((unsigned)lane << 1);

    __half c0, c1, c2, c3, c4, c5, c6, c7;
    __half n0, n1, n2, n3, n4, n5, n6, n7;
    LOAD8(c, 0);                              // batch 0 in flight during sum

    float s = rdlane_f(wave_sum63(ex), 63);
    float inv_s = __frcp_rn(s);

    float acc = 0.0f;
    int j = 0;
    while (true) {
        bool more = (j + 8) < degu;
        if (more) LOAD8(n, j + 8);
        FMA8(c, j);
        j += 8;
        if (!more) break;
        bool more2 = (j + 8) < degu;
        if (more2) LOAD8(c, j + 8);
        FMA8(n, j);
        j += 8;
        if (!more2) break;
    }
    acc *= inv_s;
    out[(size_t)d * D + lane] = acc + fv + bv;
}

extern "C" void kernel_launch(void* const* d_in, const int* in_sizes, int n_in,
                              void* d_out, int out_size, void* d_ws, size_t ws_size,
                              hipStream_t stream) {
    const float* feat   = (const float*)d_in[0];
    const float* W      = (const float*)d_in[1];
    const float* attn_l = (const float*)d_in[2];
    const float* attn_r = (const float*)d_in[3];
    const float* bias   = (const float*)d_in[4];
    const int*   src    = (const int*)d_in[5];
    const int*   dst    = (const int*)d_in[6];
    float* out = (float*)d_out;

    char* ws = (char*)d_ws;
    __half*   ft     = (__half*)(ws);                // 12,800,000
    float*    el     = (float*)(ws + 12800000);      // 400,000
    float*    er     = (float*)(ws + 13200000);      // 400,000
    int*      perm   = (int*)(ws + 13600000);        // 8,007,680 -> 21,607,680
    uint2*    rowBE  = (uint2*)(ws + 21607680);      // 800,000 -> 22,407,680
    unsigned* bcnt   = (unsigned*)(ws + 22407680);   // 1,564 -> 22,409,244
    unsigned* binned = (unsigned*)(ws + 22409248);   // 8,007,680 -> 30,416,928
    float*    eperm  = (float*)binned;               // aliases binned (LDS-staged)

    k_zero<<<2, 256, 0, stream>>>(bcnt);
    k_bg<<<NBIN + NTILE, 256, 0, stream>>>(src, dst, bcnt, binned,
                                           feat, W, attn_l, attn_r, el, er);
    k_sg<<<NBKT + NTILE, 256, 0, stream>>>(bcnt, binned, el, er,
                                           perm, eperm, rowBE, feat, W, ft);
    k_agg<<<(NN * 64 + 255) / 256, 256, 0, stream>>>(rowBE, perm, eperm,
                                                     ft, feat, bias, out);
}